// Round 5
// baseline (377.259 us; speedup 1.0000x reference)
//
#include <hip/hip_runtime.h>

typedef __attribute__((ext_vector_type(8))) __bf16 bf16x8;
typedef __attribute__((ext_vector_type(8))) unsigned short u16x8;
typedef __attribute__((ext_vector_type(4))) float f32x4;

// Static device scratch (bf16):
//  xbf [2048][2048], WtQKV [3072][2048], WtO [2048][2048],
//  q [2048][2048], k [2048][512], v [2048][512], att [2048][2048]
#define XBOFF 0
#define WQKVOFF (XBOFF + 2048 * 2048)
#define WOOFF   (WQKVOFF + 3072 * 2048)
#define QOFF    (WOOFF + 2048 * 2048)
#define KOFF    (QOFF + 2048 * 2048)
#define VOFF    (KOFF + 2048 * 512)
#define AOFF    (VOFF + 2048 * 512)
__device__ ushort g_scratch[AOFF + 2048 * 2048];

// nested (matryoshka) index -> full-layout index, H heads/groups, 128/head
__device__ __forceinline__ int nest_map(int n, int H) {
    int h = n >> 7, j = n & 127;
    if (j < 32) return h * 32 + j;
    if (j < 64) return H * 32 + h * 32 + (j - 32);
    return H * 64 + h * 64 + (j - 64);
}

__device__ __forceinline__ ushort f2bf(float f) {
    unsigned u = __builtin_bit_cast(unsigned, f);
    u += 0x7fffu + ((u >> 16) & 1u);
    return (ushort)(u >> 16);
}
__device__ __forceinline__ bf16x8 ld_frag(const ushort* p) {
    return __builtin_bit_cast(bf16x8, *(const u16x8*)p);
}

// ---------------------------------------------------------------------------
// x fp32 -> bf16 (elementwise). 2048 blocks x 256 thr x 8 elems.
// ---------------------------------------------------------------------------
__global__ __launch_bounds__(256) void cvt_x_kernel(const float* __restrict__ x)
{
    size_t i = ((size_t)blockIdx.x * 256 + threadIdx.x) * 8;
    float4 f0 = *(const float4*)&x[i];
    float4 f1 = *(const float4*)&x[i + 4];
    union { uint4 v; ushort u[8]; } a;
    a.u[0] = f2bf(f0.x); a.u[1] = f2bf(f0.y); a.u[2] = f2bf(f0.z); a.u[3] = f2bf(f0.w);
    a.u[4] = f2bf(f1.x); a.u[5] = f2bf(f1.y); a.u[6] = f2bf(f1.z); a.u[7] = f2bf(f1.w);
    *(uint4*)&g_scratch[XBOFF + i] = a.v;
}

// ---------------------------------------------------------------------------
// Weight transpose+convert, nest reorder folded in.
// mode 0: Wt[n][k] = W[k][nest_map(n,H)]  (QKV, column-mapped)
// mode 1: Wt[n][k] = W[nest_map(k,16)][n] (O, row-mapped)
// grid (K/64, N/64). Wt rows are 2048 (=K) wide. dstoff = ushort offset.
// ---------------------------------------------------------------------------
__global__ __launch_bounds__(256) void transpose_w_kernel(
    const float* __restrict__ W, int rowlen, int H, int mode, int dstoff)
{
    __shared__ ushort T[64][66];
    const int k0 = blockIdx.x * 64;
    const int n0 = blockIdx.y * 64;
    const int t = threadIdx.x;
    const int r = t >> 3, oct = t & 7;

    #pragma unroll
    for (int rep = 0; rep < 2; ++rep) {
        int rr = r + rep * 32;
        int wrow = mode ? nest_map(k0 + rr, 16) : (k0 + rr);
        int wcol = mode ? (n0 + oct * 8) : nest_map(n0 + oct * 8, H);
        float4 f0 = *(const float4*)&W[(size_t)wrow * rowlen + wcol];
        float4 f1 = *(const float4*)&W[(size_t)wrow * rowlen + wcol + 4];
        ushort* d = &T[rr][oct * 8];
        d[0] = f2bf(f0.x); d[1] = f2bf(f0.y); d[2] = f2bf(f0.z); d[3] = f2bf(f0.w);
        d[4] = f2bf(f1.x); d[5] = f2bf(f1.y); d[6] = f2bf(f1.z); d[7] = f2bf(f1.w);
    }
    __syncthreads();
    #pragma unroll
    for (int rep = 0; rep < 2; ++rep) {
        int rr = r + rep * 32;
        union { uint4 v; ushort u[8]; } cv;
        #pragma unroll
        for (int i = 0; i < 8; ++i) cv.u[i] = T[oct * 8 + i][rr];
        *(uint4*)&g_scratch[dstoff + (size_t)(n0 + rr) * 2048 + k0 + oct * 8] = cv.v;
    }
}

// ---------------------------------------------------------------------------
// 128x128-tile GEMM (m93 structure): C = A[2048][2048] * Bt^T, BK=64,
// 4 waves (2x2), each wave 64x64 via 4x4 MFMA tiles, all-b128 LDS reads.
// mode 0: A=xbf, Bt=WtQKV (N=3072), out -> q|k|v bf16, fp32 bias nest-mapped.
// mode 1: A=att, Bt=WtO (N=2048), out -> fp32 d_out, bias direct.
// ---------------------------------------------------------------------------
__global__ __launch_bounds__(256) void gemm128_kernel(
    const float* __restrict__ b0, const float* __restrict__ b1,
    const float* __restrict__ b2, float* __restrict__ oext, int mode)
{
    __shared__ ushort As[128][72];
    __shared__ ushort Bs[128][72];
    const int n0 = blockIdx.x * 128;
    const int m0 = blockIdx.y * 128;
    const int tid = threadIdx.x;
    const int lane = tid & 63, wid = tid >> 6;
    const int wm = wid & 1, wn = wid >> 1;
    const int quad = lane >> 4, l16 = lane & 15;
    const int srow = tid & 127, sch = (tid >> 7) * 4;

    const ushort* A  = g_scratch + (mode ? AOFF : XBOFF);
    const ushort* Bt = g_scratch + (mode ? WOOFF : WQKVOFF);

    // epilogue routing (block-uniform)
    const float* bias; ushort* outS = nullptr; int c0, oldim, H;
    if (mode == 1)      { bias = b0; c0 = n0; oldim = 2048; H = 0; }
    else if (n0 < 2048) { bias = b0; outS = g_scratch + QOFF; c0 = n0;        oldim = 2048; H = 16; }
    else if (n0 < 2560) { bias = b1; outS = g_scratch + KOFF; c0 = n0 - 2048; oldim = 512;  H = 4; }
    else                { bias = b2; outS = g_scratch + VOFF; c0 = n0 - 2560; oldim = 512;  H = 4; }

    f32x4 acc[4][4];
    #pragma unroll
    for (int a = 0; a < 4; ++a)
        #pragma unroll
        for (int c = 0; c < 4; ++c) acc[a][c] = f32x4{0.f, 0.f, 0.f, 0.f};

    for (int kt = 0; kt < 32; ++kt) {
        const int k0 = kt * 64;
        #pragma unroll
        for (int i = 0; i < 4; ++i) {
            int ch = sch + i;
            *(uint4*)&As[srow][ch * 8] =
                *(const uint4*)&A[(size_t)(m0 + srow) * 2048 + k0 + ch * 8];
            *(uint4*)&Bs[srow][ch * 8] =
                *(const uint4*)&Bt[(size_t)(n0 + srow) * 2048 + k0 + ch * 8];
        }
        __syncthreads();
        #pragma unroll
        for (int kc = 0; kc < 2; ++kc) {
            bf16x8 af[4], bf[4];
            #pragma unroll
            for (int s = 0; s < 4; ++s) {
                af[s] = ld_frag(&As[wm * 64 + s * 16 + l16][kc * 32 + quad * 8]);
                bf[s] = ld_frag(&Bs[wn * 64 + s * 16 + l16][kc * 32 + quad * 8]);
            }
            #pragma unroll
            for (int sm = 0; sm < 4; ++sm)
                #pragma unroll
                for (int sn = 0; sn < 4; ++sn)
                    acc[sm][sn] = __builtin_amdgcn_mfma_f32_16x16x32_bf16(
                        af[sm], bf[sn], acc[sm][sn], 0, 0, 0);
        }
        __syncthreads();
    }

    #pragma unroll
    for (int sm = 0; sm < 4; ++sm)
    #pragma unroll
    for (int sn = 0; sn < 4; ++sn)
    #pragma unroll
    for (int i = 0; i < 4; ++i) {
        int row = m0 + wm * 64 + sm * 16 + quad * 4 + i;
        int loc = wn * 64 + sn * 16 + l16;
        float v = acc[sm][sn][i];
        if (mode == 1) {
            oext[(size_t)row * 2048 + c0 + loc] = v + bias[c0 + loc];
        } else {
            v += bias[nest_map(c0 + loc, H)];
            outS[(size_t)row * oldim + c0 + loc] = f2bf(v);
        }
    }
}

// ---------------------------------------------------------------------------
// Matryoshka flash attention. Grid (16,16,2), 4 waves; wave w owns q-rows
// [w*16, w*16+16). qt = 15 - blockIdx.x (heavy tiles dispatch first).
// Q fragments live in registers (loaded once); Ps round-trip is wave-private
// (no barriers); 2 barriers per k-tile total.
// ---------------------------------------------------------------------------
__global__ __launch_bounds__(256) void attn_kernel()
{
    const ushort* qb = g_scratch + QOFF;   // [B,S,16,128] nested
    const ushort* kb = g_scratch + KOFF;   // [B,S,4,128]
    const ushort* vb = g_scratch + VOFF;   // [B,S,4,128]
    ushort* att = g_scratch + AOFF;        // [B,S,16,128] nested

    __shared__ ushort Ks[64][136];
    __shared__ ushort Vt[128][72];   // V transposed, XOR-octet swizzled
    __shared__ ushort Ps[64][72];    // P round-trip (wave-private rows)

    const int qt = 15 - blockIdx.x, h = blockIdx.y, b = blockIdx.z;
    const int g = h >> 2;
    const int q0 = qt * 64;
    const int tid = threadIdx.x;
    const int lane = tid & 63, w = tid >> 6;
    const int quad = lane >> 4, l16 = lane & 15;

    // Q fragments: registers, loaded once (row = q0 + w*16 + l16)
    bf16x8 qa[4];
    {
        const ushort* qrow =
            qb + ((size_t)((b * 1024 + q0 + w * 16 + l16) * 16 + h)) * 128;
        #pragma unroll
        for (int kc = 0; kc < 4; ++kc)
            qa[kc] = ld_frag(qrow + kc * 32 + quad * 8);
    }

    float m_s[3][4], l_s[3][4];
    #pragma unroll
    for (int l = 0; l < 3; ++l)
        #pragma unroll
        for (int i = 0; i < 4; ++i) { m_s[l][i] = -1e9f; l_s[l][i] = 0.0f; }
    f32x4 oacc[8];
    #pragma unroll
    for (int t2 = 0; t2 < 8; ++t2) oacc[t2] = f32x4{0.f, 0.f, 0.f, 0.f};

    f32x4 sdp[4];
    const f32x4 fz = {0.f, 0.f, 0.f, 0.f};

    auto attn_level = [&](int lvl, float scale, int obase, int ontiles, int voff,
                          bool diag, int k0) {
        float sv[4][4], mx[4];
        #pragma unroll
        for (int i = 0; i < 4; ++i) mx[i] = -1e9f;
        #pragma unroll
        for (int n = 0; n < 4; ++n)
            #pragma unroll
            for (int i = 0; i < 4; ++i) {
                float x = sdp[n][i] * scale;
                if (diag) {
                    int kc = k0 + n * 16 + l16;
                    int qr = q0 + w * 16 + quad * 4 + i;
                    if (kc > qr) x = -1e9f;
                }
                sv[n][i] = x;
                mx[i] = fmaxf(mx[i], x);
            }
        #pragma unroll
        for (int d = 1; d < 16; d <<= 1)
            #pragma unroll
            for (int i = 0; i < 4; ++i) mx[i] = fmaxf(mx[i], __shfl_xor(mx[i], d, 64));
        float al[4], rs[4];
        #pragma unroll
        for (int i = 0; i < 4; ++i) {
            float mn = fmaxf(m_s[lvl][i], mx[i]);
            al[i] = __expf(m_s[lvl][i] - mn);
            m_s[lvl][i] = mn;
            rs[i] = 0.f;
        }
        #pragma unroll
        for (int n = 0; n < 4; ++n)
            #pragma unroll
            for (int i = 0; i < 4; ++i) {
                float p = __expf(sv[n][i] - m_s[lvl][i]);
                sv[n][i] = p;
                rs[i] += p;
            }
        #pragma unroll
        for (int d = 1; d < 16; d <<= 1)
            #pragma unroll
            for (int i = 0; i < 4; ++i) rs[i] += __shfl_xor(rs[i], d, 64);
        #pragma unroll
        for (int i = 0; i < 4; ++i) l_s[lvl][i] = l_s[lvl][i] * al[i] + rs[i];
        for (int t = 0; t < ontiles; ++t)
            #pragma unroll
            for (int i = 0; i < 4; ++i) oacc[obase + t][i] *= al[i];
        // P: C-layout regs -> LDS rows [w*16, w*16+16) (wave-private; the
        // hardware/compiler orders same-wave LDS RAW via lgkmcnt)
        #pragma unroll
        for (int n = 0; n < 4; ++n)
            #pragma unroll
            for (int i = 0; i < 4; ++i)
                Ps[w * 16 + quad * 4 + i][n * 16 + l16] = f2bf(sv[n][i]);
        // PV: A = P (A-layout), B = V (swizzled Vt)
        #pragma unroll
        for (int kc = 0; kc < 2; ++kc) {
            bf16x8 pa = ld_frag(&Ps[w * 16 + l16][kc * 32 + quad * 8]);
            for (int t = 0; t < ontiles; ++t) {
                int vd = voff + t * 16 + l16;
                bf16x8 vf = ld_frag(&Vt[vd][(kc * 32 + quad * 8) ^ (((vd >> 3) & 7) << 3)]);
                oacc[obase + t] =
                    __builtin_amdgcn_mfma_f32_16x16x32_bf16(pa, vf, oacc[obase + t], 0, 0, 0);
            }
        }
    };

    for (int kt = 0; kt <= qt; ++kt) {
        const int k0 = kt * 64;
        {   // stage K natural, V transposed+swizzled
            int r = tid >> 4, oct = tid & 15;
            #pragma unroll
            for (int rep = 0; rep < 4; ++rep) {
                int row = r + rep * 16;
                size_t base = (size_t)((b * 1024 + k0 + row) * 4 + g) * 128 + oct * 8;
                *(uint4*)&Ks[row][oct * 8] = *(const uint4*)&kb[base];
                union { uint4 v; ushort u[8]; } cv;
                cv.v = *(const uint4*)&vb[base];
                #pragma unroll
                for (int i = 0; i < 8; ++i) {
                    int d = oct * 8 + i;
                    Vt[d][row ^ (((d >> 3) & 7) << 3)] = cv.u[i];
                }
            }
        }
        __syncthreads();

        const bool diag = (kt == qt);
        #pragma unroll
        for (int n = 0; n < 4; ++n)
            sdp[n] = __builtin_amdgcn_mfma_f32_16x16x32_bf16(
                qa[0], ld_frag(&Ks[n * 16 + l16][quad * 8]), fz, 0, 0, 0);
        attn_level(0, 0.1767766953f, 0, 2, 0, diag, k0);
        #pragma unroll
        for (int n = 0; n < 4; ++n)
            sdp[n] = __builtin_amdgcn_mfma_f32_16x16x32_bf16(
                qa[1], ld_frag(&Ks[n * 16 + l16][32 + quad * 8]), sdp[n], 0, 0, 0);
        attn_level(1, 0.125f, 2, 2, 32, diag, k0);
        #pragma unroll
        for (int kc = 2; kc < 4; ++kc)
            #pragma unroll
            for (int n = 0; n < 4; ++n)
                sdp[n] = __builtin_amdgcn_mfma_f32_16x16x32_bf16(
                    qa[kc], ld_frag(&Ks[n * 16 + l16][kc * 32 + quad * 8]), sdp[n], 0, 0, 0);
        attn_level(2, 0.0883883476f, 4, 4, 64, diag, k0);

        __syncthreads();   // WAR: Ks/Vt reads done before next staging
    }

    float inv[3][4];
    #pragma unroll
    for (int l = 0; l < 3; ++l)
        #pragma unroll
        for (int i = 0; i < 4; ++i) {
            float L = l_s[l][i];
            inv[l][i] = (L > 0.f) ? (1.0f / L) : 0.f;
        }
    #pragma unroll
    for (int t = 0; t < 8; ++t) {
        int lvl = (t < 2) ? 0 : (t < 4) ? 1 : 2;
        #pragma unroll
        for (int i = 0; i < 4; ++i) {
            int srow = q0 + w * 16 + quad * 4 + i;
            att[(size_t)((b * 1024 + srow) * 16 + h) * 128 + t * 16 + l16] =
                f2bf(oacc[t][i] * inv[lvl][i]);
        }
    }
}

// ---------------------------------------------------------------------------
extern "C" void kernel_launch(void* const* d_in, const int* in_sizes, int n_in,
                              void* d_out, int out_size, void* d_ws, size_t ws_size,
                              hipStream_t stream)
{
    const float* x  = (const float*)d_in[0];
    // d_in[1] = mask (bool tril): applied analytically — unused
    const float* Wq = (const float*)d_in[2];
    const float* bq = (const float*)d_in[3];
    const float* Wk = (const float*)d_in[4];
    const float* bk = (const float*)d_in[5];
    const float* Wv = (const float*)d_in[6];
    const float* bv = (const float*)d_in[7];
    const float* Wo = (const float*)d_in[8];
    const float* bo = (const float*)d_in[9];
    float* out = (float*)d_out;
    (void)d_ws; (void)ws_size;

    dim3 blk(256, 1, 1);
    hipLaunchKernelGGL(cvt_x_kernel, dim3(2048), blk, 0, stream, x);
    hipLaunchKernelGGL(transpose_w_kernel, dim3(32, 32), blk, 0, stream,
                       Wq, 2048, 16, 0, WQKVOFF);
    hipLaunchKernelGGL(transpose_w_kernel, dim3(32, 8), blk, 0, stream,
                       Wk, 512, 4, 0, WQKVOFF + 2048 * 2048);
    hipLaunchKernelGGL(transpose_w_kernel, dim3(32, 8), blk, 0, stream,
                       Wv, 512, 4, 0, WQKVOFF + 2560 * 2048);
    hipLaunchKernelGGL(transpose_w_kernel, dim3(32, 32), blk, 0, stream,
                       Wo, 2048, 16, 1, WOOFF);
    hipLaunchKernelGGL(gemm128_kernel, dim3(24, 16), blk, 0, stream,
                       bq, bk, bv, (float*)nullptr, 0);
    hipLaunchKernelGGL(attn_kernel, dim3(16, 16, 2), blk, 0, stream);
    hipLaunchKernelGGL(gemm128_kernel, dim3(16, 16), blk, 0, stream,
                       bo, nullptr, nullptr, out, 1);
}